// Round 2
// baseline (546.932 us; speedup 1.0000x reference)
//
#include <hip/hip_runtime.h>

// ---------------------------------------------------------------------------
// WindowAttention fused kernel for MI355X (gfx950). FP32 I/O per reference:
//   x         [2048][49][256] f32      mask   [64][49][49] f32
//   qkv_w     [256][768] f32           qkv_b  [768] f32
//   proj_w    [256][256] f32           proj_b [256] f32
//   bias_table[169][8] f32             rel_index [2401] i32
//   out       [2048][49][256] f32
// Internals: bf16 MFMA (16x16x32), fp32 accumulate, exp2-domain softmax.
// v3: 3 blocks/CU. LDS 79584 -> 54096 B via (a) V held in registers and
//     PV B-frags built with __shfl quad-permutes (no V LDS), (b) q/k
//     stride 36 read as 2x ds_read_b64, (c) x-staging overlaid on waves
//     0-1's private regions. CB inner dim permuted so softmax bias is one
//     float4 load per row.
// ---------------------------------------------------------------------------

typedef __attribute__((ext_vector_type(8))) short v8s;   // 8 x bf16 (4 VGPRs)
typedef __attribute__((ext_vector_type(4))) short v4s;   // 4 x bf16
typedef __attribute__((ext_vector_type(4))) float v4f;   // MFMA accumulator

__device__ __forceinline__ unsigned short f2bf(float f) {   // RNE f32->bf16
    union { float f; unsigned int i; } v; v.f = f;
    unsigned int x = v.i;
    return (unsigned short)((x + 0x7fffu + ((x >> 16) & 1u)) >> 16);
}
__device__ __forceinline__ unsigned int pk2bf(float a, float b) {
    return (unsigned int)f2bf(a) | ((unsigned int)f2bf(b) << 16);
}

#define NW1 196608              // W1f elements (48 tiles * 8 ksteps * 64 lanes * 8)
#define NW2 65536               // W2f elements (16 tiles * 8 ksteps * 64 lanes * 8)
#define NB1 768                 // B1v elements
#define NCB 1605632             // CBf elements (64*8*49*64), fp32
#define QSCALE_LOG2E 0.25503487f   // (1/sqrt(32)) * log2(e)
#define LOG2E 1.4426950408889634f

// ---------------------------------------------------------------------------
// Preprocessing: fragment-linear bf16 weights + fp32 combined bias/mask.
// CB inner dim is PERMUTED for vectorized softmax loads:
//   CBf[w][h][row][c] holds value for key column c_old = (c&3)*16 + (c>>2)
// so lane l15 reads its 4 values (nt=0..3 <-> cols nt*16+l15) as one float4
// at offset l15*4.
// ---------------------------------------------------------------------------
__global__ void wattn_preproc(const float* __restrict__ qkv_w,
                              const float* __restrict__ qkv_b,
                              const float* __restrict__ proj_w,
                              const float* __restrict__ bias_table,
                              const float* __restrict__ mask,
                              const int* __restrict__ rel_index,
                              unsigned short* __restrict__ W1f,
                              unsigned short* __restrict__ W2f,
                              float* __restrict__ B1v,
                              float* __restrict__ CBf)
{
    const int idx = blockIdx.x * 256 + threadIdx.x;
    if (idx < NW1) {
        const int j = idx & 7, l = (idx >> 3) & 63, s = (idx >> 9) & 7, T = idx >> 12;
        const int k = s * 32 + (l >> 4) * 8 + j;
        const int n = T * 16 + (l & 15);
        const int hh = n / 96, sub = n % 96;
        const int col = (sub < 32) ? (hh * 32 + sub)
                      : (sub < 64) ? (256 + hh * 32 + (sub - 32))
                                   : (512 + hh * 32 + (sub - 64));
        float v = qkv_w[k * 768 + col];
        if (sub < 32) v *= QSCALE_LOG2E;
        W1f[idx] = f2bf(v);
    } else if (idx < NW1 + NW2) {
        const int t = idx - NW1;
        const int j = t & 7, l = (t >> 3) & 63, s = (t >> 9) & 7, T = t >> 12;
        const int k = s * 32 + (l >> 4) * 8 + j;
        const int n = T * 16 + (l & 15);
        W2f[t] = f2bf(proj_w[k * 256 + n]);
    } else if (idx < NW1 + NW2 + NB1) {
        const int n = idx - NW1 - NW2;
        const int hh = n / 96, sub = n % 96;
        const int col = (sub < 32) ? (hh * 32 + sub)
                      : (sub < 64) ? (256 + hh * 32 + (sub - 32))
                                   : (512 + hh * 32 + (sub - 64));
        float v = qkv_b[col];
        if (sub < 32) v *= QSCALE_LOG2E;
        B1v[n] = v;
    } else {
        const int t = idx - (NW1 + NW2 + NB1);
        if (t < NCB) {
            const int c = t & 63;
            const int rr = t >> 6;
            const int r = rr % 49;
            const int q2 = rr / 49;
            const int hh = q2 & 7;
            const int w = q2 >> 3;
            const int c_old = ((c & 3) << 4) | (c >> 2);   // permuted inner dim
            float v;
            if (c_old < 49) {
                const int ri = rel_index[r * 49 + c_old];
                v = (bias_table[ri * 8 + hh] + mask[(w * 49 + r) * 49 + c_old]) * LOG2E;
            } else {
                v = -1e30f;
            }
            CBf[t] = v;
        }
    }
}

// ---------------------------------------------------------------------------
// Main fused kernel: one block (4 waves) per window, 3 blocks/CU.
// Per-wave private LDS region Wr (3528 shorts = 7056 B), overlaid lifetimes:
//   phase A: q [0,1764)  k [1764,3528)   ([49][36] each, 2x ds_read_b64)
//   phase B: P [0,3528)                  ([49][72], b128-aligned)
// V never touches LDS: PV B-frags are built from the QKV accumulator via
// __shfl quad-permutes. x staging buffer xs[49][136] overlays wreg[0..1].
// ---------------------------------------------------------------------------
__global__ __launch_bounds__(256, 3)
void wattn_main(const float* __restrict__ x,
                const unsigned short* __restrict__ W1f,
                const float* __restrict__ B1v,
                const float* __restrict__ CB,
                const unsigned short* __restrict__ W2f,
                const float* __restrict__ proj_b,
                float* __restrict__ out)
{
    // LDS total = 28224 + 25872 = 54096 B -> 3 blocks/CU (3*~54272 <= 163840)
    __shared__ __align__(16) unsigned short wreg[4 * 3528]; // per-wave q/k then P
    __shared__ __align__(16) unsigned short Os[49 * 264];   // attn out [token][256]
    unsigned short* const xs = wreg;                        // overlay: x chunk [49][136]

    const int tid  = threadIdx.x;
    const int wave = tid >> 6;
    const int lane = tid & 63;
    const int quad = lane >> 4;
    const int l15  = lane & 15;
    const int b    = blockIdx.x;
    const int widx = b & 63;
    const float* xw = x + (long)b * 49 * 256;
    const v4f zero4 = {0.0f, 0.0f, 0.0f, 0.0f};
    unsigned short* const Wr = wreg + wave * 3528;

    // A-frag row bases into xs (clamped pad rows)
    int arow[4];
    #pragma unroll
    for (int mt = 0; mt < 4; ++mt) {
        int m = mt * 16 + l15; if (m > 48) m = 48;
        arow[mt] = m * 136 + quad * 8;
    }

    // ---- two GEMM+attention phases; wave w owns head (p*4 + w) ----
    #pragma unroll 1
    for (int p = 0; p < 2; ++p) {
        v4f acc[6][4];
        #pragma unroll
        for (int i = 0; i < 6; ++i)
            #pragma unroll
            for (int mt = 0; mt < 4; ++mt) acc[i][mt] = zero4;

        const int T0 = p * 24 + wave * 6;
        const unsigned short* bb = W1f + T0 * 4096 + lane * 8;

        // QKV GEMM over K=256 in two 128-col chunks
        #pragma unroll 1
        for (int ch = 0; ch < 2; ++ch) {
            __syncthreads();   // previous consumers of xs (and waves 0/1 P) done
            // stage x[:, ch*128 .. +128) -> bf16 LDS (coalesced float4 loads)
            for (int i = tid; i < 1568; i += 256) {
                const int r = i >> 5, cq = i & 31;
                const float4 v = *reinterpret_cast<const float4*>(xw + r * 256 + ch * 128 + cq * 4);
                ushort4 o;
                o.x = f2bf(v.x); o.y = f2bf(v.y); o.z = f2bf(v.z); o.w = f2bf(v.w);
                *reinterpret_cast<ushort4*>(&xs[r * 136 + cq * 4]) = o;
            }
            __syncthreads();
            #pragma unroll
            for (int s = 0; s < 4; ++s) {
                v8s afr[4];
                #pragma unroll
                for (int mt = 0; mt < 4; ++mt)
                    afr[mt] = *reinterpret_cast<const v8s*>(&xs[arow[mt] + s * 32]);
                v8s bfr[6];
                #pragma unroll
                for (int i = 0; i < 6; ++i)
                    bfr[i] = *reinterpret_cast<const v8s*>(bb + i * 4096 + (ch * 4 + s) * 512);
                #pragma unroll
                for (int i = 0; i < 6; ++i)
                    #pragma unroll
                    for (int mt = 0; mt < 4; ++mt)
                        acc[i][mt] = __builtin_amdgcn_mfma_f32_16x16x32_bf16(afr[mt], bfr[i], acc[i][mt], 0, 0, 0);
            }
        }
        // qkv bias
        #pragma unroll
        for (int i = 0; i < 6; ++i) {
            const float bv = B1v[(T0 + i) * 16 + l15];
            #pragma unroll
            for (int mt = 0; mt < 4; ++mt) {
                acc[i][mt].x += bv; acc[i][mt].y += bv; acc[i][mt].z += bv; acc[i][mt].w += bv;
            }
        }

        // pack V (acc tiles 4,5) into bf16 pairs; acc[4..5] dead after this
        unsigned int vpk[2][4][2];
        #pragma unroll
        for (int iv = 0; iv < 2; ++iv)
            #pragma unroll
            for (int mt = 0; mt < 4; ++mt) {
                vpk[iv][mt][0] = pk2bf(acc[4 + iv][mt][0], acc[4 + iv][mt][1]);
                vpk[iv][mt][1] = pk2bf(acc[4 + iv][mt][2], acc[4 + iv][mt][3]);
            }

        __syncthreads();   // all waves' xs reads done; safe to scatter into wreg

        // ================= per-wave attention (no block barriers) =============
        const int h = p * 4 + wave;

        // scatter q,k (C-layout acc -> row-major [token][d], stride 36)
        #pragma unroll
        for (int i = 0; i < 4; ++i) {
            const int base = (i < 2) ? 0 : 1764;
            const int c = (i & 1) * 16 + l15;
            #pragma unroll
            for (int mt = 0; mt < 4; ++mt) {
                const int m0 = mt * 16 + quad * 4;
                #pragma unroll
                for (int r = 0; r < 4; ++r)
                    if (m0 + r < 49) Wr[base + (m0 + r) * 36 + c] = f2bf(acc[i][mt][r]);
            }
        }

        // QK^T: 4x4 tiles, K=32 in one step (rows via 2x ds_read_b64)
        v8s aq[4], bk[4];
        #pragma unroll
        for (int t = 0; t < 4; ++t) {
            int rq = t * 16 + l15; if (rq > 48) rq = 48;
            const int qo = rq * 36 + quad * 8;
            const v4s qlo = *reinterpret_cast<const v4s*>(&Wr[qo]);
            const v4s qhi = *reinterpret_cast<const v4s*>(&Wr[qo + 4]);
            aq[t] = __builtin_shufflevector(qlo, qhi, 0, 1, 2, 3, 4, 5, 6, 7);
            const v4s klo = *reinterpret_cast<const v4s*>(&Wr[1764 + qo]);
            const v4s khi = *reinterpret_cast<const v4s*>(&Wr[1764 + qo + 4]);
            bk[t] = __builtin_shufflevector(klo, khi, 0, 1, 2, 3, 4, 5, 6, 7);
        }
        v4f sacc[4][4];
        #pragma unroll
        for (int mt = 0; mt < 4; ++mt)
            #pragma unroll
            for (int nt = 0; nt < 4; ++nt)
                sacc[mt][nt] = __builtin_amdgcn_mfma_f32_16x16x32_bf16(aq[mt], bk[nt], zero4, 0, 0, 0);

        // in-register softmax (exp2 domain) + P write (P overlays q/k, stride 72)
        const float* cbb = CB + ((long)widx * 8 + h) * 49 * 64;
        #pragma unroll
        for (int mt = 0; mt < 4; ++mt) {
            #pragma unroll
            for (int r = 0; r < 4; ++r) {
                const int m = mt * 16 + quad * 4 + r;
                const int mc = m > 48 ? 48 : m;
                const float4 cb4 = *reinterpret_cast<const float4*>(cbb + mc * 64 + l15 * 4);
                float s0 = sacc[mt][0][r] + cb4.x;
                float s1 = sacc[mt][1][r] + cb4.y;
                float s2 = sacc[mt][2][r] + cb4.z;
                float s3 = sacc[mt][3][r] + cb4.w;
                float mx = fmaxf(fmaxf(s0, s1), fmaxf(s2, s3));
                #pragma unroll
                for (int off = 1; off < 16; off <<= 1) mx = fmaxf(mx, __shfl_xor(mx, off, 16));
                const float e0 = __builtin_exp2f(s0 - mx);
                const float e1 = __builtin_exp2f(s1 - mx);
                const float e2 = __builtin_exp2f(s2 - mx);
                const float e3 = __builtin_exp2f(s3 - mx);
                float sm = (e0 + e1) + (e2 + e3);
                #pragma unroll
                for (int off = 1; off < 16; off <<= 1) sm += __shfl_xor(sm, off, 16);
                const float rs = __builtin_amdgcn_rcpf(sm);
                if (m < 49) {
                    Wr[m * 72 + l15]      = f2bf(e0 * rs);
                    Wr[m * 72 + 16 + l15] = f2bf(e1 * rs);
                    Wr[m * 72 + 32 + l15] = f2bf(e2 * rs);
                    Wr[m * 72 + 48 + l15] = f2bf(e3 * rs);
                }
            }
        }

        // build PV B-frags from vpk via quad-permutes (no V LDS).
        // B-frag lane (quad,l15), k-slot j: token kt*32+quad*8+j, col iv*16+l15.
        // source lane ((quad&1)*2 + (j>>2))*16 + l15, tile mtA = 2kt+(quad>>1).
        const int srcA = ((quad & 1) << 5) + l15;
        v8s bvf[2][2];
        #pragma unroll
        for (int kt = 0; kt < 2; ++kt) {
            #pragma unroll
            for (int iv = 0; iv < 2; ++iv) {
                union { unsigned int u[4]; v8s v; } bw;
                #pragma unroll
                for (int hw = 0; hw < 2; ++hw) {
                    const unsigned int aA = (unsigned int)__shfl((int)vpk[iv][2 * kt][hw],     srcA);
                    const unsigned int bA = (unsigned int)__shfl((int)vpk[iv][2 * kt + 1][hw], srcA);
                    bw.u[hw] = (quad & 2) ? bA : aA;
                    const unsigned int aB = (unsigned int)__shfl((int)vpk[iv][2 * kt][hw],     srcA + 16);
                    const unsigned int bB = (unsigned int)__shfl((int)vpk[iv][2 * kt + 1][hw], srcA + 16);
                    bw.u[2 + hw] = (quad & 2) ? bB : aB;
                }
                bvf[kt][iv] = bw.v;
            }
        }

        // P @ V   (pad key tokens 49..63 have P==0, so garbage V cols are inert)
        #pragma unroll
        for (int mt = 0; mt < 4; ++mt) {
            int mrc = mt * 16 + l15; if (mrc > 48) mrc = 48;
            v4f oacc[2] = {zero4, zero4};
            #pragma unroll
            for (int kt = 0; kt < 2; ++kt) {
                const v8s ap = *reinterpret_cast<const v8s*>(&Wr[mrc * 72 + kt * 32 + quad * 8]);
                oacc[0] = __builtin_amdgcn_mfma_f32_16x16x32_bf16(ap, bvf[kt][0], oacc[0], 0, 0, 0);
                oacc[1] = __builtin_amdgcn_mfma_f32_16x16x32_bf16(ap, bvf[kt][1], oacc[1], 0, 0, 0);
            }
            #pragma unroll
            for (int n2 = 0; n2 < 2; ++n2) {
                const int c = h * 32 + n2 * 16 + l15;
                #pragma unroll
                for (int r = 0; r < 4; ++r) {
                    const int m = mt * 16 + quad * 4 + r;
                    if (m < 49) Os[m * 264 + c] = f2bf(oacc[n2][r]);
                }
            }
        }
    } // p

    __syncthreads();

    // ---- projection: Os[49(->64)][256] @ proj_w -> out (fp32) ----
    v4f pacc[4][4];
    #pragma unroll
    for (int i = 0; i < 4; ++i)
        #pragma unroll
        for (int mt = 0; mt < 4; ++mt) pacc[i][mt] = zero4;

    int orow[4];
    #pragma unroll
    for (int mt = 0; mt < 4; ++mt) {
        int m = mt * 16 + l15; if (m > 48) m = 48;
        orow[mt] = m * 264 + quad * 8;
    }
    const unsigned short* wb = W2f + (wave * 4) * 4096 + lane * 8;

    #pragma unroll
    for (int s = 0; s < 8; ++s) {
        v8s afr[4];
        #pragma unroll
        for (int mt = 0; mt < 4; ++mt)
            afr[mt] = *reinterpret_cast<const v8s*>(&Os[orow[mt] + s * 32]);
        #pragma unroll
        for (int i = 0; i < 4; ++i) {
            const v8s bfp = *reinterpret_cast<const v8s*>(wb + i * 4096 + s * 512);
            #pragma unroll
            for (int mt = 0; mt < 4; ++mt)
                pacc[i][mt] = __builtin_amdgcn_mfma_f32_16x16x32_bf16(afr[mt], bfp, pacc[i][mt], 0, 0, 0);
        }
    }

    #pragma unroll
    for (int i = 0; i < 4; ++i) {
        const int c = (wave * 4 + i) * 16 + l15;
        const float pb = proj_b[c];
        #pragma unroll
        for (int mt = 0; mt < 4; ++mt) {
            #pragma unroll
            for (int r = 0; r < 4; ++r) {
                const int m = mt * 16 + quad * 4 + r;
                if (m < 49) out[((long)b * 49 + m) * 256 + c] = pacc[i][mt][r] + pb;
            }
        }
    }
}

// ---------------------------------------------------------------------------
extern "C" void kernel_launch(void* const* d_in, const int* in_sizes, int n_in,
                              void* d_out, int out_size, void* d_ws, size_t ws_size,
                              hipStream_t stream)
{
    const float* x          = (const float*)d_in[0];
    const float* mask       = (const float*)d_in[1];
    const float* qkv_w      = (const float*)d_in[2];
    const float* qkv_b      = (const float*)d_in[3];
    const float* proj_w     = (const float*)d_in[4];
    const float* proj_b     = (const float*)d_in[5];
    const float* bias_table = (const float*)d_in[6];
    const int*   rel_index  = (const int*)d_in[7];
    float* out = (float*)d_out;

    char* ws = (char*)d_ws;
    unsigned short* W1f = (unsigned short*)(ws);             // 393216 B
    unsigned short* W2f = (unsigned short*)(ws + 393216);    // 131072 B
    float*          B1v = (float*)(ws + 524288);             //   3072 B
    float*          CBf = (float*)(ws + 527360);             // 6422528 B (total ~6.95 MB)

    // 196608 + 65536 + 768 + 1605632 = 1868544 = 7299 * 256 exactly
    wattn_preproc<<<7299, 256, 0, stream>>>(qkv_w, qkv_b, proj_w, bias_table, mask,
                                            rel_index, W1f, W2f, B1v, CBf);
    wattn_main<<<2048, 256, 0, stream>>>(x, W1f, B1v, CBf, W2f, proj_b, out);
}

// Round 3
// 457.775 us; speedup vs baseline: 1.1948x; 1.1948x over previous
//
#include <hip/hip_runtime.h>

// ---------------------------------------------------------------------------
// WindowAttention fused kernel for MI355X (gfx950). FP32 I/O per reference:
//   x         [2048][49][256] f32      mask   [64][49][49] f32
//   qkv_w     [256][768] f32           qkv_b  [768] f32
//   proj_w    [256][256] f32           proj_b [256] f32
//   bias_table[169][8] f32             rel_index [2401] i32
//   out       [2048][49][256] f32
// Internals: bf16 MFMA (16x16x32), fp32 accumulate, exp2-domain softmax.
// v4: v3's 54096-B LDS layout (3 blocks/CU) + register-pressure fixes:
//     (a) QK^T/softmax streamed per m-tile (sacc[4] not [4][4]),
//     (b) GEMM s-loop unroll capped at 2 (stop load-hoist reg blowup).
//     Goal: no scratch spills under __launch_bounds__(256,3).
// ---------------------------------------------------------------------------

typedef __attribute__((ext_vector_type(8))) short v8s;   // 8 x bf16 (4 VGPRs)
typedef __attribute__((ext_vector_type(4))) short v4s;   // 4 x bf16
typedef __attribute__((ext_vector_type(4))) float v4f;   // MFMA accumulator

__device__ __forceinline__ unsigned short f2bf(float f) {   // RNE f32->bf16
    union { float f; unsigned int i; } v; v.f = f;
    unsigned int x = v.i;
    return (unsigned short)((x + 0x7fffu + ((x >> 16) & 1u)) >> 16);
}
__device__ __forceinline__ unsigned int pk2bf(float a, float b) {
    return (unsigned int)f2bf(a) | ((unsigned int)f2bf(b) << 16);
}

#define NW1 196608              // W1f elements (48 tiles * 8 ksteps * 64 lanes * 8)
#define NW2 65536               // W2f elements (16 tiles * 8 ksteps * 64 lanes * 8)
#define NB1 768                 // B1v elements
#define NCB 1605632             // CBf elements (64*8*49*64), fp32
#define QSCALE_LOG2E 0.25503487f   // (1/sqrt(32)) * log2(e)
#define LOG2E 1.4426950408889634f

// ---------------------------------------------------------------------------
// Preprocessing: fragment-linear bf16 weights + fp32 combined bias/mask.
// CB inner dim is PERMUTED for vectorized softmax loads:
//   CBf[w][h][row][c] holds value for key column c_old = (c&3)*16 + (c>>2)
// so lane l15 reads its 4 values (nt=0..3 <-> cols nt*16+l15) as one float4
// at offset l15*4.
// ---------------------------------------------------------------------------
__global__ void wattn_preproc(const float* __restrict__ qkv_w,
                              const float* __restrict__ qkv_b,
                              const float* __restrict__ proj_w,
                              const float* __restrict__ bias_table,
                              const float* __restrict__ mask,
                              const int* __restrict__ rel_index,
                              unsigned short* __restrict__ W1f,
                              unsigned short* __restrict__ W2f,
                              float* __restrict__ B1v,
                              float* __restrict__ CBf)
{
    const int idx = blockIdx.x * 256 + threadIdx.x;
    if (idx < NW1) {
        const int j = idx & 7, l = (idx >> 3) & 63, s = (idx >> 9) & 7, T = idx >> 12;
        const int k = s * 32 + (l >> 4) * 8 + j;
        const int n = T * 16 + (l & 15);
        const int hh = n / 96, sub = n % 96;
        const int col = (sub < 32) ? (hh * 32 + sub)
                      : (sub < 64) ? (256 + hh * 32 + (sub - 32))
                                   : (512 + hh * 32 + (sub - 64));
        float v = qkv_w[k * 768 + col];
        if (sub < 32) v *= QSCALE_LOG2E;
        W1f[idx] = f2bf(v);
    } else if (idx < NW1 + NW2) {
        const int t = idx - NW1;
        const int j = t & 7, l = (t >> 3) & 63, s = (t >> 9) & 7, T = t >> 12;
        const int k = s * 32 + (l >> 4) * 8 + j;
        const int n = T * 16 + (l & 15);
        W2f[t] = f2bf(proj_w[k * 256 + n]);
    } else if (idx < NW1 + NW2 + NB1) {
        const int n = idx - NW1 - NW2;
        const int hh = n / 96, sub = n % 96;
        const int col = (sub < 32) ? (hh * 32 + sub)
                      : (sub < 64) ? (256 + hh * 32 + (sub - 32))
                                   : (512 + hh * 32 + (sub - 64));
        float v = qkv_b[col];
        if (sub < 32) v *= QSCALE_LOG2E;
        B1v[n] = v;
    } else {
        const int t = idx - (NW1 + NW2 + NB1);
        if (t < NCB) {
            const int c = t & 63;
            const int rr = t >> 6;
            const int r = rr % 49;
            const int q2 = rr / 49;
            const int hh = q2 & 7;
            const int w = q2 >> 3;
            const int c_old = ((c & 3) << 4) | (c >> 2);   // permuted inner dim
            float v;
            if (c_old < 49) {
                const int ri = rel_index[r * 49 + c_old];
                v = (bias_table[ri * 8 + hh] + mask[(w * 49 + r) * 49 + c_old]) * LOG2E;
            } else {
                v = -1e30f;
            }
            CBf[t] = v;
        }
    }
}

// ---------------------------------------------------------------------------
// Main fused kernel: one block (4 waves) per window, 3 blocks/CU.
// Per-wave private LDS region Wr (3528 shorts = 7056 B), overlaid lifetimes:
//   phase A: q [0,1764)  k [1764,3528)   ([49][36] each, 2x ds_read_b64)
//   phase B: P [0,3528)                  ([49][72], b128-aligned)
// V never touches LDS: PV B-frags are built from the QKV accumulator via
// __shfl quad-permutes. x staging buffer xs[49][136] overlays wreg[0..1].
// ---------------------------------------------------------------------------
__global__ __launch_bounds__(256, 3)
void wattn_main(const float* __restrict__ x,
                const unsigned short* __restrict__ W1f,
                const float* __restrict__ B1v,
                const float* __restrict__ CB,
                const unsigned short* __restrict__ W2f,
                const float* __restrict__ proj_b,
                float* __restrict__ out)
{
    // LDS total = 28224 + 25872 = 54096 B -> 3 blocks/CU (3*~54272 <= 163840)
    __shared__ __align__(16) unsigned short wreg[4 * 3528]; // per-wave q/k then P
    __shared__ __align__(16) unsigned short Os[49 * 264];   // attn out [token][256]
    unsigned short* const xs = wreg;                        // overlay: x chunk [49][136]

    const int tid  = threadIdx.x;
    const int wave = tid >> 6;
    const int lane = tid & 63;
    const int quad = lane >> 4;
    const int l15  = lane & 15;
    const int b    = blockIdx.x;
    const int widx = b & 63;
    const float* xw = x + (long)b * 49 * 256;
    const v4f zero4 = {0.0f, 0.0f, 0.0f, 0.0f};
    unsigned short* const Wr = wreg + wave * 3528;

    // A-frag row bases into xs (clamped pad rows)
    int arow[4];
    #pragma unroll
    for (int mt = 0; mt < 4; ++mt) {
        int m = mt * 16 + l15; if (m > 48) m = 48;
        arow[mt] = m * 136 + quad * 8;
    }

    // ---- two GEMM+attention phases; wave w owns head (p*4 + w) ----
    #pragma unroll 1
    for (int p = 0; p < 2; ++p) {
        v4f acc[6][4];
        #pragma unroll
        for (int i = 0; i < 6; ++i)
            #pragma unroll
            for (int mt = 0; mt < 4; ++mt) acc[i][mt] = zero4;

        const int T0 = p * 24 + wave * 6;
        const unsigned short* bb = W1f + T0 * 4096 + lane * 8;

        // QKV GEMM over K=256 in two 128-col chunks
        #pragma unroll 1
        for (int ch = 0; ch < 2; ++ch) {
            __syncthreads();   // previous consumers of xs (and waves 0/1 P) done
            // stage x[:, ch*128 .. +128) -> bf16 LDS (coalesced float4 loads)
            for (int i = tid; i < 1568; i += 256) {
                const int r = i >> 5, cq = i & 31;
                const float4 v = *reinterpret_cast<const float4*>(xw + r * 256 + ch * 128 + cq * 4);
                ushort4 o;
                o.x = f2bf(v.x); o.y = f2bf(v.y); o.z = f2bf(v.z); o.w = f2bf(v.w);
                *reinterpret_cast<ushort4*>(&xs[r * 136 + cq * 4]) = o;
            }
            __syncthreads();
            #pragma unroll 2   // cap load-hoisting: full unroll spilled (v3)
            for (int s = 0; s < 4; ++s) {
                v8s afr[4];
                #pragma unroll
                for (int mt = 0; mt < 4; ++mt)
                    afr[mt] = *reinterpret_cast<const v8s*>(&xs[arow[mt] + s * 32]);
                v8s bfr[6];
                #pragma unroll
                for (int i = 0; i < 6; ++i)
                    bfr[i] = *reinterpret_cast<const v8s*>(bb + i * 4096 + (ch * 4 + s) * 512);
                #pragma unroll
                for (int i = 0; i < 6; ++i)
                    #pragma unroll
                    for (int mt = 0; mt < 4; ++mt)
                        acc[i][mt] = __builtin_amdgcn_mfma_f32_16x16x32_bf16(afr[mt], bfr[i], acc[i][mt], 0, 0, 0);
            }
        }
        // qkv bias
        #pragma unroll
        for (int i = 0; i < 6; ++i) {
            const float bv = B1v[(T0 + i) * 16 + l15];
            #pragma unroll
            for (int mt = 0; mt < 4; ++mt) {
                acc[i][mt].x += bv; acc[i][mt].y += bv; acc[i][mt].z += bv; acc[i][mt].w += bv;
            }
        }

        // pack V (acc tiles 4,5) into bf16 pairs; acc[4..5] dead after this
        unsigned int vpk[2][4][2];
        #pragma unroll
        for (int iv = 0; iv < 2; ++iv)
            #pragma unroll
            for (int mt = 0; mt < 4; ++mt) {
                vpk[iv][mt][0] = pk2bf(acc[4 + iv][mt][0], acc[4 + iv][mt][1]);
                vpk[iv][mt][1] = pk2bf(acc[4 + iv][mt][2], acc[4 + iv][mt][3]);
            }

        __syncthreads();   // all waves' xs reads done; safe to scatter into wreg

        // ================= per-wave attention (no block barriers) =============
        const int h = p * 4 + wave;

        // scatter q,k (C-layout acc -> row-major [token][d], stride 36)
        #pragma unroll
        for (int i = 0; i < 4; ++i) {
            const int base = (i < 2) ? 0 : 1764;
            const int c = (i & 1) * 16 + l15;
            #pragma unroll
            for (int mt = 0; mt < 4; ++mt) {
                const int m0 = mt * 16 + quad * 4;
                #pragma unroll
                for (int r = 0; r < 4; ++r)
                    if (m0 + r < 49) Wr[base + (m0 + r) * 36 + c] = f2bf(acc[i][mt][r]);
            }
        }

        // preload ALL QK^T fragments (q/k region is overwritten by P below)
        v8s aq[4], bk[4];
        #pragma unroll
        for (int t = 0; t < 4; ++t) {
            int rq = t * 16 + l15; if (rq > 48) rq = 48;
            const int qo = rq * 36 + quad * 8;
            const v4s qlo = *reinterpret_cast<const v4s*>(&Wr[qo]);
            const v4s qhi = *reinterpret_cast<const v4s*>(&Wr[qo + 4]);
            aq[t] = __builtin_shufflevector(qlo, qhi, 0, 1, 2, 3, 4, 5, 6, 7);
            const v4s klo = *reinterpret_cast<const v4s*>(&Wr[1764 + qo]);
            const v4s khi = *reinterpret_cast<const v4s*>(&Wr[1764 + qo + 4]);
            bk[t] = __builtin_shufflevector(klo, khi, 0, 1, 2, 3, 4, 5, 6, 7);
        }

        // QK^T + softmax, STREAMED per m-tile (sacc[4] live, not [4][4]).
        // P (stride 72) overlays the q/k region -- safe, frags preloaded.
        const float* cbb = CB + ((long)widx * 8 + h) * 49 * 64;
        #pragma unroll 2
        for (int mt = 0; mt < 4; ++mt) {
            v4f sacc[4];
            #pragma unroll
            for (int nt = 0; nt < 4; ++nt)
                sacc[nt] = __builtin_amdgcn_mfma_f32_16x16x32_bf16(aq[mt], bk[nt], zero4, 0, 0, 0);
            #pragma unroll
            for (int r = 0; r < 4; ++r) {
                const int m = mt * 16 + quad * 4 + r;
                const int mc = m > 48 ? 48 : m;
                const float4 cb4 = *reinterpret_cast<const float4*>(cbb + mc * 64 + l15 * 4);
                float s0 = sacc[0][r] + cb4.x;
                float s1 = sacc[1][r] + cb4.y;
                float s2 = sacc[2][r] + cb4.z;
                float s3 = sacc[3][r] + cb4.w;
                float mx = fmaxf(fmaxf(s0, s1), fmaxf(s2, s3));
                #pragma unroll
                for (int off = 1; off < 16; off <<= 1) mx = fmaxf(mx, __shfl_xor(mx, off, 16));
                const float e0 = __builtin_exp2f(s0 - mx);
                const float e1 = __builtin_exp2f(s1 - mx);
                const float e2 = __builtin_exp2f(s2 - mx);
                const float e3 = __builtin_exp2f(s3 - mx);
                float sm = (e0 + e1) + (e2 + e3);
                #pragma unroll
                for (int off = 1; off < 16; off <<= 1) sm += __shfl_xor(sm, off, 16);
                const float rs = __builtin_amdgcn_rcpf(sm);
                if (m < 49) {
                    Wr[m * 72 + l15]      = f2bf(e0 * rs);
                    Wr[m * 72 + 16 + l15] = f2bf(e1 * rs);
                    Wr[m * 72 + 32 + l15] = f2bf(e2 * rs);
                    Wr[m * 72 + 48 + l15] = f2bf(e3 * rs);
                }
            }
        }

        // build PV B-frags from vpk via quad-permutes (no V LDS).
        // B-frag lane (quad,l15), k-slot j: token kt*32+quad*8+j, col iv*16+l15.
        // source lane ((quad&1)*2 + (j>>2))*16 + l15, tile mtA = 2kt+(quad>>1).
        const int srcA = ((quad & 1) << 5) + l15;
        v8s bvf[2][2];
        #pragma unroll
        for (int kt = 0; kt < 2; ++kt) {
            #pragma unroll
            for (int iv = 0; iv < 2; ++iv) {
                union { unsigned int u[4]; v8s v; } bw;
                #pragma unroll
                for (int hw = 0; hw < 2; ++hw) {
                    const unsigned int aA = (unsigned int)__shfl((int)vpk[iv][2 * kt][hw],     srcA);
                    const unsigned int bA = (unsigned int)__shfl((int)vpk[iv][2 * kt + 1][hw], srcA);
                    bw.u[hw] = (quad & 2) ? bA : aA;
                    const unsigned int aB = (unsigned int)__shfl((int)vpk[iv][2 * kt][hw],     srcA + 16);
                    const unsigned int bB = (unsigned int)__shfl((int)vpk[iv][2 * kt + 1][hw], srcA + 16);
                    bw.u[2 + hw] = (quad & 2) ? bB : aB;
                }
                bvf[kt][iv] = bw.v;
            }
        }

        // P @ V   (pad key tokens 49..63 have P==0, so garbage V cols are inert)
        #pragma unroll
        for (int mt = 0; mt < 4; ++mt) {
            int mrc = mt * 16 + l15; if (mrc > 48) mrc = 48;
            v4f oacc[2] = {zero4, zero4};
            #pragma unroll
            for (int kt = 0; kt < 2; ++kt) {
                const v8s ap = *reinterpret_cast<const v8s*>(&Wr[mrc * 72 + kt * 32 + quad * 8]);
                oacc[0] = __builtin_amdgcn_mfma_f32_16x16x32_bf16(ap, bvf[kt][0], oacc[0], 0, 0, 0);
                oacc[1] = __builtin_amdgcn_mfma_f32_16x16x32_bf16(ap, bvf[kt][1], oacc[1], 0, 0, 0);
            }
            #pragma unroll
            for (int n2 = 0; n2 < 2; ++n2) {
                const int c = h * 32 + n2 * 16 + l15;
                #pragma unroll
                for (int r = 0; r < 4; ++r) {
                    const int m = mt * 16 + quad * 4 + r;
                    if (m < 49) Os[m * 264 + c] = f2bf(oacc[n2][r]);
                }
            }
        }
    } // p

    __syncthreads();

    // ---- projection: Os[49(->64)][256] @ proj_w -> out (fp32) ----
    v4f pacc[4][4];
    #pragma unroll
    for (int i = 0; i < 4; ++i)
        #pragma unroll
        for (int mt = 0; mt < 4; ++mt) pacc[i][mt] = zero4;

    int orow[4];
    #pragma unroll
    for (int mt = 0; mt < 4; ++mt) {
        int m = mt * 16 + l15; if (m > 48) m = 48;
        orow[mt] = m * 264 + quad * 8;
    }
    const unsigned short* wb = W2f + (wave * 4) * 4096 + lane * 8;

    #pragma unroll 2
    for (int s = 0; s < 8; ++s) {
        v8s afr[4];
        #pragma unroll
        for (int mt = 0; mt < 4; ++mt)
            afr[mt] = *reinterpret_cast<const v8s*>(&Os[orow[mt] + s * 32]);
        #pragma unroll
        for (int i = 0; i < 4; ++i) {
            const v8s bfp = *reinterpret_cast<const v8s*>(wb + i * 4096 + s * 512);
            #pragma unroll
            for (int mt = 0; mt < 4; ++mt)
                pacc[i][mt] = __builtin_amdgcn_mfma_f32_16x16x32_bf16(afr[mt], bfp, pacc[i][mt], 0, 0, 0);
        }
    }

    #pragma unroll
    for (int i = 0; i < 4; ++i) {
        const int c = (wave * 4 + i) * 16 + l15;
        const float pb = proj_b[c];
        #pragma unroll
        for (int mt = 0; mt < 4; ++mt) {
            #pragma unroll
            for (int r = 0; r < 4; ++r) {
                const int m = mt * 16 + quad * 4 + r;
                if (m < 49) out[((long)b * 49 + m) * 256 + c] = pacc[i][mt][r] + pb;
            }
        }
    }
}

// ---------------------------------------------------------------------------
extern "C" void kernel_launch(void* const* d_in, const int* in_sizes, int n_in,
                              void* d_out, int out_size, void* d_ws, size_t ws_size,
                              hipStream_t stream)
{
    const float* x          = (const float*)d_in[0];
    const float* mask       = (const float*)d_in[1];
    const float* qkv_w      = (const float*)d_in[2];
    const float* qkv_b      = (const float*)d_in[3];
    const float* proj_w     = (const float*)d_in[4];
    const float* proj_b     = (const float*)d_in[5];
    const float* bias_table = (const float*)d_in[6];
    const int*   rel_index  = (const int*)d_in[7];
    float* out = (float*)d_out;

    char* ws = (char*)d_ws;
    unsigned short* W1f = (unsigned short*)(ws);             // 393216 B
    unsigned short* W2f = (unsigned short*)(ws + 393216);    // 131072 B
    float*          B1v = (float*)(ws + 524288);             //   3072 B
    float*          CBf = (float*)(ws + 527360);             // 6422528 B (total ~6.95 MB)

    // 196608 + 65536 + 768 + 1605632 = 1868544 = 7299 * 256 exactly
    wattn_preproc<<<7299, 256, 0, stream>>>(qkv_w, qkv_b, proj_w, bias_table, mask,
                                            rel_index, W1f, W2f, B1v, CBf);
    wattn_main<<<2048, 256, 0, stream>>>(x, W1f, B1v, CBf, W2f, proj_b, out);
}

// Round 4
// 406.907 us; speedup vs baseline: 1.3441x; 1.1250x over previous
//
#include <hip/hip_runtime.h>

// ---------------------------------------------------------------------------
// WindowAttention fused kernel for MI355X (gfx950). FP32 I/O per reference:
//   x         [2048][49][256] f32      mask   [64][49][49] f32
//   qkv_w     [256][768] f32           qkv_b  [768] f32
//   proj_w    [256][256] f32           proj_b [256] f32
//   bias_table[169][8] f32             rel_index [2401] i32
//   out       [2048][49][256] f32
// Internals: bf16 MFMA (16x16x32), fp32 accumulate, exp2-domain softmax.
// v5: v4's 54096-B LDS layout + streamed softmax, but with the proven
//     __launch_bounds__(256,2) register budget (v3/v4's (256,3) made hipcc
//     clamp to 84 VGPRs -> scratch spills -> slower AND no extra block).
//     3 blocks/CU must come from natural fit: LDS 3*54272<=163840 and
//     VGPR ~130*12<=2048.
// ---------------------------------------------------------------------------

typedef __attribute__((ext_vector_type(8))) short v8s;   // 8 x bf16 (4 VGPRs)
typedef __attribute__((ext_vector_type(4))) short v4s;   // 4 x bf16
typedef __attribute__((ext_vector_type(4))) float v4f;   // MFMA accumulator

__device__ __forceinline__ unsigned short f2bf(float f) {   // RNE f32->bf16
    union { float f; unsigned int i; } v; v.f = f;
    unsigned int x = v.i;
    return (unsigned short)((x + 0x7fffu + ((x >> 16) & 1u)) >> 16);
}
__device__ __forceinline__ unsigned int pk2bf(float a, float b) {
    return (unsigned int)f2bf(a) | ((unsigned int)f2bf(b) << 16);
}

#define NW1 196608              // W1f elements (48 tiles * 8 ksteps * 64 lanes * 8)
#define NW2 65536               // W2f elements (16 tiles * 8 ksteps * 64 lanes * 8)
#define NB1 768                 // B1v elements
#define NCB 1605632             // CBf elements (64*8*49*64), fp32
#define QSCALE_LOG2E 0.25503487f   // (1/sqrt(32)) * log2(e)
#define LOG2E 1.4426950408889634f

// ---------------------------------------------------------------------------
// Preprocessing: fragment-linear bf16 weights + fp32 combined bias/mask.
// CB inner dim is PERMUTED for vectorized softmax loads:
//   CBf[w][h][row][c] holds value for key column c_old = (c&3)*16 + (c>>2)
// so lane l15 reads its 4 values (nt=0..3 <-> cols nt*16+l15) as one float4
// at offset l15*4.
// ---------------------------------------------------------------------------
__global__ void wattn_preproc(const float* __restrict__ qkv_w,
                              const float* __restrict__ qkv_b,
                              const float* __restrict__ proj_w,
                              const float* __restrict__ bias_table,
                              const float* __restrict__ mask,
                              const int* __restrict__ rel_index,
                              unsigned short* __restrict__ W1f,
                              unsigned short* __restrict__ W2f,
                              float* __restrict__ B1v,
                              float* __restrict__ CBf)
{
    const int idx = blockIdx.x * 256 + threadIdx.x;
    if (idx < NW1) {
        const int j = idx & 7, l = (idx >> 3) & 63, s = (idx >> 9) & 7, T = idx >> 12;
        const int k = s * 32 + (l >> 4) * 8 + j;
        const int n = T * 16 + (l & 15);
        const int hh = n / 96, sub = n % 96;
        const int col = (sub < 32) ? (hh * 32 + sub)
                      : (sub < 64) ? (256 + hh * 32 + (sub - 32))
                                   : (512 + hh * 32 + (sub - 64));
        float v = qkv_w[k * 768 + col];
        if (sub < 32) v *= QSCALE_LOG2E;
        W1f[idx] = f2bf(v);
    } else if (idx < NW1 + NW2) {
        const int t = idx - NW1;
        const int j = t & 7, l = (t >> 3) & 63, s = (t >> 9) & 7, T = t >> 12;
        const int k = s * 32 + (l >> 4) * 8 + j;
        const int n = T * 16 + (l & 15);
        W2f[t] = f2bf(proj_w[k * 256 + n]);
    } else if (idx < NW1 + NW2 + NB1) {
        const int n = idx - NW1 - NW2;
        const int hh = n / 96, sub = n % 96;
        const int col = (sub < 32) ? (hh * 32 + sub)
                      : (sub < 64) ? (256 + hh * 32 + (sub - 32))
                                   : (512 + hh * 32 + (sub - 64));
        float v = qkv_b[col];
        if (sub < 32) v *= QSCALE_LOG2E;
        B1v[n] = v;
    } else {
        const int t = idx - (NW1 + NW2 + NB1);
        if (t < NCB) {
            const int c = t & 63;
            const int rr = t >> 6;
            const int r = rr % 49;
            const int q2 = rr / 49;
            const int hh = q2 & 7;
            const int w = q2 >> 3;
            const int c_old = ((c & 3) << 4) | (c >> 2);   // permuted inner dim
            float v;
            if (c_old < 49) {
                const int ri = rel_index[r * 49 + c_old];
                v = (bias_table[ri * 8 + hh] + mask[(w * 49 + r) * 49 + c_old]) * LOG2E;
            } else {
                v = -1e30f;
            }
            CBf[t] = v;
        }
    }
}

// ---------------------------------------------------------------------------
// Main fused kernel: one block (4 waves) per window.
// Per-wave private LDS region Wr (3528 shorts = 7056 B), overlaid lifetimes:
//   phase A: q [0,1764)  k [1764,3528)   ([49][36] each, 2x ds_read_b64)
//   phase B: P [0,3528)                  ([49][72], b128-aligned)
// V never touches LDS: PV B-frags are built from the QKV accumulator via
// __shfl quad-permutes. x staging buffer xs[49][136] overlays wreg[0..1].
// ---------------------------------------------------------------------------
__global__ __launch_bounds__(256, 2)
void wattn_main(const float* __restrict__ x,
                const unsigned short* __restrict__ W1f,
                const float* __restrict__ B1v,
                const float* __restrict__ CB,
                const unsigned short* __restrict__ W2f,
                const float* __restrict__ proj_b,
                float* __restrict__ out)
{
    // LDS total = 28224 + 25872 = 54096 B -> 3 blocks/CU if VGPR <= ~170
    __shared__ __align__(16) unsigned short wreg[4 * 3528]; // per-wave q/k then P
    __shared__ __align__(16) unsigned short Os[49 * 264];   // attn out [token][256]
    unsigned short* const xs = wreg;                        // overlay: x chunk [49][136]

    const int tid  = threadIdx.x;
    const int wave = tid >> 6;
    const int lane = tid & 63;
    const int quad = lane >> 4;
    const int l15  = lane & 15;
    const int b    = blockIdx.x;
    const int widx = b & 63;
    const float* xw = x + (long)b * 49 * 256;
    const v4f zero4 = {0.0f, 0.0f, 0.0f, 0.0f};
    unsigned short* const Wr = wreg + wave * 3528;

    // A-frag row bases into xs (clamped pad rows)
    int arow[4];
    #pragma unroll
    for (int mt = 0; mt < 4; ++mt) {
        int m = mt * 16 + l15; if (m > 48) m = 48;
        arow[mt] = m * 136 + quad * 8;
    }

    // ---- two GEMM+attention phases; wave w owns head (p*4 + w) ----
    #pragma unroll 1
    for (int p = 0; p < 2; ++p) {
        v4f acc[6][4];
        #pragma unroll
        for (int i = 0; i < 6; ++i)
            #pragma unroll
            for (int mt = 0; mt < 4; ++mt) acc[i][mt] = zero4;

        const int T0 = p * 24 + wave * 6;
        const unsigned short* bb = W1f + T0 * 4096 + lane * 8;

        // QKV GEMM over K=256 in two 128-col chunks
        #pragma unroll 1
        for (int ch = 0; ch < 2; ++ch) {
            __syncthreads();   // previous consumers of xs (and waves 0/1 P) done
            // stage x[:, ch*128 .. +128) -> bf16 LDS (coalesced float4 loads)
            for (int i = tid; i < 1568; i += 256) {
                const int r = i >> 5, cq = i & 31;
                const float4 v = *reinterpret_cast<const float4*>(xw + r * 256 + ch * 128 + cq * 4);
                ushort4 o;
                o.x = f2bf(v.x); o.y = f2bf(v.y); o.z = f2bf(v.z); o.w = f2bf(v.w);
                *reinterpret_cast<ushort4*>(&xs[r * 136 + cq * 4]) = o;
            }
            __syncthreads();
            #pragma unroll 2   // cap load-hoisting (full unroll blew regs in v3)
            for (int s = 0; s < 4; ++s) {
                v8s afr[4];
                #pragma unroll
                for (int mt = 0; mt < 4; ++mt)
                    afr[mt] = *reinterpret_cast<const v8s*>(&xs[arow[mt] + s * 32]);
                v8s bfr[6];
                #pragma unroll
                for (int i = 0; i < 6; ++i)
                    bfr[i] = *reinterpret_cast<const v8s*>(bb + i * 4096 + (ch * 4 + s) * 512);
                #pragma unroll
                for (int i = 0; i < 6; ++i)
                    #pragma unroll
                    for (int mt = 0; mt < 4; ++mt)
                        acc[i][mt] = __builtin_amdgcn_mfma_f32_16x16x32_bf16(afr[mt], bfr[i], acc[i][mt], 0, 0, 0);
            }
        }
        // qkv bias
        #pragma unroll
        for (int i = 0; i < 6; ++i) {
            const float bv = B1v[(T0 + i) * 16 + l15];
            #pragma unroll
            for (int mt = 0; mt < 4; ++mt) {
                acc[i][mt].x += bv; acc[i][mt].y += bv; acc[i][mt].z += bv; acc[i][mt].w += bv;
            }
        }

        // pack V (acc tiles 4,5) into bf16 pairs; acc[4..5] dead after this
        unsigned int vpk[2][4][2];
        #pragma unroll
        for (int iv = 0; iv < 2; ++iv)
            #pragma unroll
            for (int mt = 0; mt < 4; ++mt) {
                vpk[iv][mt][0] = pk2bf(acc[4 + iv][mt][0], acc[4 + iv][mt][1]);
                vpk[iv][mt][1] = pk2bf(acc[4 + iv][mt][2], acc[4 + iv][mt][3]);
            }

        __syncthreads();   // all waves' xs reads done; safe to scatter into wreg

        // ================= per-wave attention (no block barriers) =============
        const int h = p * 4 + wave;

        // scatter q,k (C-layout acc -> row-major [token][d], stride 36)
        #pragma unroll
        for (int i = 0; i < 4; ++i) {
            const int base = (i < 2) ? 0 : 1764;
            const int c = (i & 1) * 16 + l15;
            #pragma unroll
            for (int mt = 0; mt < 4; ++mt) {
                const int m0 = mt * 16 + quad * 4;
                #pragma unroll
                for (int r = 0; r < 4; ++r)
                    if (m0 + r < 49) Wr[base + (m0 + r) * 36 + c] = f2bf(acc[i][mt][r]);
            }
        }

        // preload ALL QK^T fragments (q/k region is overwritten by P below)
        v8s aq[4], bk[4];
        #pragma unroll
        for (int t = 0; t < 4; ++t) {
            int rq = t * 16 + l15; if (rq > 48) rq = 48;
            const int qo = rq * 36 + quad * 8;
            const v4s qlo = *reinterpret_cast<const v4s*>(&Wr[qo]);
            const v4s qhi = *reinterpret_cast<const v4s*>(&Wr[qo + 4]);
            aq[t] = __builtin_shufflevector(qlo, qhi, 0, 1, 2, 3, 4, 5, 6, 7);
            const v4s klo = *reinterpret_cast<const v4s*>(&Wr[1764 + qo]);
            const v4s khi = *reinterpret_cast<const v4s*>(&Wr[1764 + qo + 4]);
            bk[t] = __builtin_shufflevector(klo, khi, 0, 1, 2, 3, 4, 5, 6, 7);
        }

        // QK^T + softmax, STREAMED per m-tile (sacc[4] live, not [4][4]).
        // P (stride 72) overlays the q/k region -- safe, frags preloaded.
        const float* cbb = CB + ((long)widx * 8 + h) * 49 * 64;
        #pragma unroll 2
        for (int mt = 0; mt < 4; ++mt) {
            v4f sacc[4];
            #pragma unroll
            for (int nt = 0; nt < 4; ++nt)
                sacc[nt] = __builtin_amdgcn_mfma_f32_16x16x32_bf16(aq[mt], bk[nt], zero4, 0, 0, 0);
            #pragma unroll
            for (int r = 0; r < 4; ++r) {
                const int m = mt * 16 + quad * 4 + r;
                const int mc = m > 48 ? 48 : m;
                const float4 cb4 = *reinterpret_cast<const float4*>(cbb + mc * 64 + l15 * 4);
                float s0 = sacc[0][r] + cb4.x;
                float s1 = sacc[1][r] + cb4.y;
                float s2 = sacc[2][r] + cb4.z;
                float s3 = sacc[3][r] + cb4.w;
                float mx = fmaxf(fmaxf(s0, s1), fmaxf(s2, s3));
                #pragma unroll
                for (int off = 1; off < 16; off <<= 1) mx = fmaxf(mx, __shfl_xor(mx, off, 16));
                const float e0 = __builtin_exp2f(s0 - mx);
                const float e1 = __builtin_exp2f(s1 - mx);
                const float e2 = __builtin_exp2f(s2 - mx);
                const float e3 = __builtin_exp2f(s3 - mx);
                float sm = (e0 + e1) + (e2 + e3);
                #pragma unroll
                for (int off = 1; off < 16; off <<= 1) sm += __shfl_xor(sm, off, 16);
                const float rs = __builtin_amdgcn_rcpf(sm);
                if (m < 49) {
                    Wr[m * 72 + l15]      = f2bf(e0 * rs);
                    Wr[m * 72 + 16 + l15] = f2bf(e1 * rs);
                    Wr[m * 72 + 32 + l15] = f2bf(e2 * rs);
                    Wr[m * 72 + 48 + l15] = f2bf(e3 * rs);
                }
            }
        }

        // build PV B-frags from vpk via quad-permutes (no V LDS).
        // B-frag lane (quad,l15), k-slot j: token kt*32+quad*8+j, col iv*16+l15.
        // source lane ((quad&1)*2 + (j>>2))*16 + l15, tile mtA = 2kt+(quad>>1).
        const int srcA = ((quad & 1) << 5) + l15;
        v8s bvf[2][2];
        #pragma unroll
        for (int kt = 0; kt < 2; ++kt) {
            #pragma unroll
            for (int iv = 0; iv < 2; ++iv) {
                union { unsigned int u[4]; v8s v; } bw;
                #pragma unroll
                for (int hw = 0; hw < 2; ++hw) {
                    const unsigned int aA = (unsigned int)__shfl((int)vpk[iv][2 * kt][hw],     srcA);
                    const unsigned int bA = (unsigned int)__shfl((int)vpk[iv][2 * kt + 1][hw], srcA);
                    bw.u[hw] = (quad & 2) ? bA : aA;
                    const unsigned int aB = (unsigned int)__shfl((int)vpk[iv][2 * kt][hw],     srcA + 16);
                    const unsigned int bB = (unsigned int)__shfl((int)vpk[iv][2 * kt + 1][hw], srcA + 16);
                    bw.u[2 + hw] = (quad & 2) ? bB : aB;
                }
                bvf[kt][iv] = bw.v;
            }
        }

        // P @ V   (pad key tokens 49..63 have P==0, so garbage V cols are inert)
        #pragma unroll
        for (int mt = 0; mt < 4; ++mt) {
            int mrc = mt * 16 + l15; if (mrc > 48) mrc = 48;
            v4f oacc[2] = {zero4, zero4};
            #pragma unroll
            for (int kt = 0; kt < 2; ++kt) {
                const v8s ap = *reinterpret_cast<const v8s*>(&Wr[mrc * 72 + kt * 32 + quad * 8]);
                oacc[0] = __builtin_amdgcn_mfma_f32_16x16x32_bf16(ap, bvf[kt][0], oacc[0], 0, 0, 0);
                oacc[1] = __builtin_amdgcn_mfma_f32_16x16x32_bf16(ap, bvf[kt][1], oacc[1], 0, 0, 0);
            }
            #pragma unroll
            for (int n2 = 0; n2 < 2; ++n2) {
                const int c = h * 32 + n2 * 16 + l15;
                #pragma unroll
                for (int r = 0; r < 4; ++r) {
                    const int m = mt * 16 + quad * 4 + r;
                    if (m < 49) Os[m * 264 + c] = f2bf(oacc[n2][r]);
                }
            }
        }
    } // p

    __syncthreads();

    // ---- projection: Os[49(->64)][256] @ proj_w -> out (fp32) ----
    v4f pacc[4][4];
    #pragma unroll
    for (int i = 0; i < 4; ++i)
        #pragma unroll
        for (int mt = 0; mt < 4; ++mt) pacc[i][mt] = zero4;

    int orow[4];
    #pragma unroll
    for (int mt = 0; mt < 4; ++mt) {
        int m = mt * 16 + l15; if (m > 48) m = 48;
        orow[mt] = m * 264 + quad * 8;
    }
    const unsigned short* wb = W2f + (wave * 4) * 4096 + lane * 8;

    #pragma unroll 2
    for (int s = 0; s < 8; ++s) {
        v8s afr[4];
        #pragma unroll
        for (int mt = 0; mt < 4; ++mt)
            afr[mt] = *reinterpret_cast<const v8s*>(&Os[orow[mt] + s * 32]);
        #pragma unroll
        for (int i = 0; i < 4; ++i) {
            const v8s bfp = *reinterpret_cast<const v8s*>(wb + i * 4096 + s * 512);
            #pragma unroll
            for (int mt = 0; mt < 4; ++mt)
                pacc[i][mt] = __builtin_amdgcn_mfma_f32_16x16x32_bf16(afr[mt], bfp, pacc[i][mt], 0, 0, 0);
        }
    }

    #pragma unroll
    for (int i = 0; i < 4; ++i) {
        const int c = (wave * 4 + i) * 16 + l15;
        const float pb = proj_b[c];
        #pragma unroll
        for (int mt = 0; mt < 4; ++mt) {
            #pragma unroll
            for (int r = 0; r < 4; ++r) {
                const int m = mt * 16 + quad * 4 + r;
                if (m < 49) out[((long)b * 49 + m) * 256 + c] = pacc[i][mt][r] + pb;
            }
        }
    }
}

// ---------------------------------------------------------------------------
extern "C" void kernel_launch(void* const* d_in, const int* in_sizes, int n_in,
                              void* d_out, int out_size, void* d_ws, size_t ws_size,
                              hipStream_t stream)
{
    const float* x          = (const float*)d_in[0];
    const float* mask       = (const float*)d_in[1];
    const float* qkv_w      = (const float*)d_in[2];
    const float* qkv_b      = (const float*)d_in[3];
    const float* proj_w     = (const float*)d_in[4];
    const float* proj_b     = (const float*)d_in[5];
    const float* bias_table = (const float*)d_in[6];
    const int*   rel_index  = (const int*)d_in[7];
    float* out = (float*)d_out;

    char* ws = (char*)d_ws;
    unsigned short* W1f = (unsigned short*)(ws);             // 393216 B
    unsigned short* W2f = (unsigned short*)(ws + 393216);    // 131072 B
    float*          B1v = (float*)(ws + 524288);             //   3072 B
    float*          CBf = (float*)(ws + 527360);             // 6422528 B (total ~6.95 MB)

    // 196608 + 65536 + 768 + 1605632 = 1868544 = 7299 * 256 exactly
    wattn_preproc<<<7299, 256, 0, stream>>>(qkv_w, qkv_b, proj_w, bias_table, mask,
                                            rel_index, W1f, W2f, B1v, CBf);
    wattn_main<<<2048, 256, 0, stream>>>(x, W1f, B1v, CBf, W2f, proj_b, out);
}